// Round 15
// baseline (1771.051 us; speedup 1.0000x reference)
//
#include <hip/hip_runtime.h>
#include <hip/hip_bf16.h>

#define BB 16
#define NN 2048
#define PP (BB*NN)
#define KNN 20

typedef __hip_bfloat16 bf16;
typedef unsigned short u16;
typedef unsigned int u32;
typedef __attribute__((ext_vector_type(8))) short s8v;   // 8 bf16 = 4 VGPR (MFMA A/B frag)
typedef __attribute__((ext_vector_type(4))) float f4v;   // MFMA C/D frag

__device__ __forceinline__ float bu2f(u16 u){ return __uint_as_float(((u32)u) << 16); }
__device__ __forceinline__ float lo16(u32 u){ return __uint_as_float(u << 16); }
__device__ __forceinline__ float hi16(u32 u){ return __uint_as_float(u & 0xffff0000u); }
__device__ __forceinline__ u16 f2bu(float f){ bf16 h = __float2bfloat16(f); return *(u16*)&h; }
__device__ __forceinline__ float lrelu(float h){ return (h >= 0.f) ? h : 0.2f*h; }

__device__ __forceinline__ u32 f2key(float f){
  u32 u = __float_as_uint(f);
  return (u & 0x80000000u) ? ~u : (u | 0x80000000u);
}
__device__ __forceinline__ float key2f(u32 k){
  u32 u = (k & 0x80000000u) ? (k & 0x7FFFFFFFu) : ~k;
  return __uint_as_float(u);
}

template<bool BF> __device__ __forceinline__ float wget(const void* p, size_t i){
  return BF ? bu2f(((const u16*)p)[i]) : ((const float*)p)[i];
}
template<bool BF> __device__ __forceinline__ void wload8(const void* p, size_t base, float w[8]){
  if (BF){
    const uint4 u = *(const uint4*)((const u16*)p + base);
    w[0]=lo16(u.x); w[1]=hi16(u.x); w[2]=lo16(u.y); w[3]=hi16(u.y);
    w[4]=lo16(u.z); w[5]=hi16(u.z); w[6]=lo16(u.w); w[7]=hi16(u.w);
  } else {
    const float4* f = (const float4*)((const float*)p + base);
    float4 a = f[0], b = f[1];
    w[0]=a.x; w[1]=a.y; w[2]=a.z; w[3]=a.w; w[4]=b.x; w[5]=b.y; w[6]=b.z; w[7]=b.w;
  }
}

__device__ __forceinline__ f4v mfma16(s8v a, s8v b, f4v c){
  return __builtin_amdgcn_mfma_f32_16x16x32_bf16(a, b, c, 0, 0, 0);
}

// load 8 weights as hi/lo bf16 fragments (lo = residual; exact-weight MFMA via 2 ops)
template<bool BF> __device__ __forceinline__ void loadFragHL(const void* p, size_t base,
                                                             s8v& hi, s8v& lo){
  if (BF){
    hi = *(const s8v*)((const u16*)p + base);
  } else {
    float w[8]; wload8<false>(p, base, w);
    #pragma unroll
    for (int i = 0; i < 8; ++i){
      u16 hb = f2bu(w[i]);
      hi[i] = (short)hb;
      lo[i] = (short)f2bu(w[i] - bu2f(hb));
    }
  }
}
// load 8 weights rounded to bf16 (single-frag)
template<bool BF> __device__ __forceinline__ s8v loadFragR(const void* p, size_t base){
  if (BF){
    return *(const s8v*)((const u16*)p + base);
  } else {
    float w[8]; wload8<false>(p, base, w);
    s8v r;
    #pragma unroll
    for (int i = 0; i < 8; ++i) r[i] = (short)f2bu(w[i]);
    return r;
  }
}
// weight frag: PRE -> pre-converted bf16 in ws; else rounded on the fly
template<bool BF, bool PRE> __device__ __forceinline__ s8v loadW(const void* p, size_t base){
  if (PRE) return *(const s8v*)((const u16*)p + base);
  else     return loadFragR<BF>(p, base);
}

// register-resident sorted (descending) top-20 insert, value+index pair (stage-1 KNN).
__device__ __forceinline__ void topk_ins(float d, u32 id, float (&tv)[KNN], u32 (&ti)[KNN]){
  float pv = 0.f; u32 pi = 0u; bool cp = false;
  #pragma unroll
  for (int t = 0; t < KNN; ++t){
    bool c = (tv[t] < d);
    float ov = tv[t]; u32 oi = ti[t];
    tv[t] = c ? (cp ? pv : d) : tv[t];
    ti[t] = c ? (cp ? pi : id) : ti[t];
    pv = ov; pi = oi; cp = c;
  }
}
// packed-key insert: key = (f2key(d) & ~0x7FF) | (2047-idx) — orders by (distance,
// smaller-index) = top_k stable tie rule.
__device__ __forceinline__ void topk_insp(u32 pk, u32 (&tv)[KNN]){
  u32 pv = 0u; bool cp = false;
  #pragma unroll
  for (int t = 0; t < KNN; ++t){
    bool c = (tv[t] < pk);
    u32 ov = tv[t];
    tv[t] = c ? (cp ? pv : pk) : tv[t];
    pv = ov; cp = c;
  }
}

// ---------------- dtype detector: bf16 (1) vs fp32 (0) ------------------------------
__global__ void k_detect(const u16* __restrict__ xr, int* __restrict__ flag){
  __shared__ int cnt;
  if (threadIdx.x == 0) cnt = 0;
  __syncthreads();
  float v = bu2f(xr[threadIdx.x * 2]);
  float a = fabsf(v);
  int ok = (a > 1e-6f && a < 1e6f) ? 1 : 0;
  atomicAdd(&cnt, ok);
  __syncthreads();
  if (threadIdx.x == 0) flag[0] = (cnt >= 160) ? 1 : 0;
}

// ---------------- weight -> bf16 pre-conversion -------------------------------------
__global__ void k_wconv(const int* __restrict__ FLAG, const void* __restrict__ src,
                        u16* __restrict__ dst, int n){
  int i = blockIdx.x*256 + threadIdx.x;
  if (i >= n) return;
  dst[i] = FLAG[0] ? ((const u16*)src)[i] : f2bu(((const float*)src)[i]);
}

// ---------------- prep: transpose x [B,3,N] -> XT [P,3] fp32, SQ, pool init ---------
template<bool BF>
__global__ void k_prep(const int* __restrict__ FLAG, const void* __restrict__ x,
                       float* __restrict__ XT, float* __restrict__ SQ,
                       u32* __restrict__ hmaxk, float* __restrict__ hsum){
  if (FLAG[0] != (BF ? 1 : 0)) return;
  int i = blockIdx.x*256 + threadIdx.x;
  if (i >= PP) return;
  int b = i / NN, n = i - b*NN;
  float s = 0.f;
  #pragma unroll
  for (int c = 0; c < 3; ++c){
    float v = wget<BF>(x, ((size_t)b*3 + c)*NN + n);
    XT[(size_t)i*3 + c] = v;
    s += v*v;
  }
  SQ[i] = s;
  if (i < BB*1024){ hmaxk[i] = 0u; hsum[i] = 0.f; }
}

// ---------------- SQ[i] = sum_c x[i,c]^2 -------------------------------------------
template<int Cin>
__global__ void k_sq(const u16* __restrict__ xin, float* __restrict__ SQ){
  int i = blockIdx.x*256 + threadIdx.x;
  if (i >= PP) return;
  const u32* r = (const u32*)(xin + (size_t)i*Cin);
  float s = 0.f;
  for (int c = 0; c < Cin/2; ++c){
    u32 u = r[c];
    float a = lo16(u), b = hi16(u);
    s += a*a; s += b*b;
  }
  SQ[i] = s;
}

// ---------------- stage-1 KNN (C=3 fp32): exact value+index (feeds x1 twice) --------
template<int C, int TC>
__global__ __launch_bounds__(256) void k_knn(const float* __restrict__ xin,
                                             const float* __restrict__ SQ,
                                             u16* __restrict__ IDX){
  __shared__ float cf[4][TC*C];
  __shared__ float csqv[4][TC];
  __shared__ float tvL[4][KNN][64];
  __shared__ u16   tiL[4][KNN][64];
  const int tid = threadIdx.x, w = tid >> 6, lane = tid & 63;
  const int b = blockIdx.y;
  const int q = blockIdx.x*64 + lane;
  const int j0 = w * 512;

  float qf[C];
  const float* xq = xin + ((size_t)b*NN + q)*C;
  #pragma unroll
  for (int c = 0; c < C; ++c) qf[c] = xq[c];
  const float sqq = SQ[b*NN + q];

  float tv[KNN]; u32 ti[KNN];
  #pragma unroll
  for (int t = 0; t < KNN; ++t){ tv[t] = -INFINITY; ti[t] = 0; }

  for (int t0 = 0; t0 < 512; t0 += TC){
    __syncthreads();
    const float* src = xin + ((size_t)b*NN + j0 + t0)*C;
    for (int k = lane; k < TC*C; k += 64) cf[w][k] = src[k];
    for (int k = lane; k < TC; k += 64) csqv[w][k] = SQ[b*NN + j0 + t0 + k];
    __syncthreads();
    for (int j = 0; j < TC; ++j){
      float dot = 0.f;
      #pragma unroll
      for (int c = 0; c < C; ++c) dot += qf[c]*cf[w][j*C + c];
      float d = 2.f*dot - sqq - csqv[w][j];
      if (d > tv[KNN-1]) topk_ins(d, (u32)(j0 + t0 + j), tv, ti);
    }
  }
  #pragma unroll
  for (int t = 0; t < KNN; ++t){ tvL[w][t][lane] = tv[t]; tiL[w][t][lane] = (u16)ti[t]; }
  __syncthreads();
  if (tid < 64){
    int p0=0,p1=0,p2=0,p3=0;
    u16* op = IDX + ((size_t)b*NN + q)*KNN;
    for (int t = 0; t < KNN; ++t){
      float v0 = tvL[0][p0][tid], v1 = tvL[1][p1][tid], v2 = tvL[2][p2][tid], v3 = tvL[3][p3][tid];
      int bs = 0; float bv = v0;
      if (v1 > bv){ bv = v1; bs = 1; }
      if (v2 > bv){ bv = v2; bs = 2; }
      if (v3 > bv){ bv = v3; bs = 3; }
      u16 bi;
      if      (bs == 0){ bi = tiL[0][p0][tid]; p0++; }
      else if (bs == 1){ bi = tiL[1][p1][tid]; p1++; }
      else if (bs == 2){ bi = tiL[2][p2][tid]; p2++; }
      else             { bi = tiL[3][p3][tid]; p3++; }
      op[t] = bi;
    }
  }
}

// ---------------- MFMA KNN (stages 2-4): packed-key top-20 --------------------------
// Block = 16 queries x 4 seg-waves (512 candidates each) -> 2048 blocks (8/CU).
template<int C>
__global__ __launch_bounds__(256) void k_knn_mfma(const u16* __restrict__ xin,
                                                  const float* __restrict__ SQ,
                                                  u16* __restrict__ IDX){
  __shared__ u32 tvL[KNN][256];        // 20 KB
  const int tid = threadIdx.x, w = tid >> 6, lane = tid & 63;
  const int quad = lane >> 4, n = lane & 15;
  const int b = blockIdx.y;
  const int q = blockIdx.x*16 + n;
  const int cbase = w * 512;           // this wave's candidate segment
  const u16* Xb = xin + (size_t)b*NN*C;

  s8v bfrag[C/32];
  #pragma unroll
  for (int kc = 0; kc < C/32; ++kc)
    bfrag[kc] = *(const s8v*)(Xb + (size_t)q*C + kc*32 + quad*8);
  const float sqq = SQ[b*NN + q];

  u32 tv[KNN];
  #pragma unroll
  for (int t = 0; t < KNN; ++t) tv[t] = 0u;

  s8v afr[C/32], afn[C/32];
  #pragma unroll
  for (int kc = 0; kc < C/32; ++kc)
    afr[kc] = *(const s8v*)(Xb + (size_t)(cbase + n)*C + kc*32 + quad*8);

  for (int ct = cbase; ct < cbase + 512; ct += 16){
    int ctn = (ct + 16 < cbase + 512) ? (ct + 16) : cbase;
    #pragma unroll
    for (int kc = 0; kc < C/32; ++kc)
      afn[kc] = *(const s8v*)(Xb + (size_t)(ctn + n)*C + kc*32 + quad*8);
    f4v sqc = *(const f4v*)&SQ[b*NN + ct + quad*4];
    f4v acc = {0.f, 0.f, 0.f, 0.f};
    #pragma unroll
    for (int kc = 0; kc < C/32; ++kc)
      acc = mfma16(afr[kc], bfrag[kc], acc);
    #pragma unroll
    for (int r = 0; r < 4; ++r){
      float d = 2.f*acc[r] - sqq - sqc[r];
      u32 pk = (f2key(d) & 0xFFFFF800u) | (2047u - (u32)(ct + quad*4 + r));
      if (pk > tv[KNN-1]) topk_insp(pk, tv);
    }
    #pragma unroll
    for (int kc = 0; kc < C/32; ++kc) afr[kc] = afn[kc];
  }
  #pragma unroll
  for (int t = 0; t < KNN; ++t) tvL[t][tid] = tv[t];
  __syncthreads();

  if (tid < 16){                        // 16-way merge (4 segs x 4 quads), keys unique
    int mq = blockIdx.x*16 + tid;
    int p[16];
    #pragma unroll
    for (int s = 0; s < 16; ++s) p[s] = 0;
    u16* op = IDX + ((size_t)b*NN + mq)*KNN;
    for (int t = 0; t < KNN; ++t){
      u32 bv = 0u; int bs = 0;
      #pragma unroll
      for (int s = 0; s < 16; ++s){
        int col = (s >> 2)*64 + (s & 3)*16 + tid;   // wave (s>>2), quad (s&3)
        u32 v = tvL[p[s]][col];
        if (v > bv){ bv = v; bs = s; }
      }
      op[t] = (u16)(2047u - (bv & 2047u)); p[bs]++;
    }
  }
}

// ---------------- EC1 direct (C=3 -> O=64): block = 4 points x 64 channels ----------
template<bool BF>
__global__ __launch_bounds__(256) void k_ec1(const int* __restrict__ FLAG,
                    const float* __restrict__ XT,
                    const u16* __restrict__ IDX1, const void* __restrict__ W1,
                    const void* __restrict__ bn1, u16* __restrict__ x1out){
  if (FLAG[0] != (BF ? 1 : 0)) return;
  __shared__ float nbx[4][21][3];
  __shared__ float W1s[384];
  __shared__ float bn1s[256];
  __shared__ u16   idxL[4][KNN];
  const int tid = threadIdx.x;
  const int g0 = blockIdx.x*4, b = g0 / NN;
  for (int k = tid; k < 384; k += 256) W1s[k] = wget<BF>(W1, k);
  if (tid < 256) bn1s[tid] = wget<BF>(bn1, tid);
  if (tid < 80){ int pt = tid/KNN, t = tid%KNN; idxL[pt][t] = IDX1[(size_t)(g0+pt)*KNN + t]; }
  __syncthreads();
  for (int k = tid; k < 4*21*3; k += 256){
    int row = k/3, c = k - row*3;
    int pt = row/21, slot = row - pt*21;
    int m = (slot < KNN) ? (int)idxL[pt][slot] : (g0 + pt - b*NN);
    nbx[pt][slot][c] = XT[((size_t)b*NN + m)*3 + c];
  }
  __syncthreads();
  int pt = tid >> 6, o = tid & 63;
  float wa0 = W1s[o*6], wa1 = W1s[o*6+1], wa2 = W1s[o*6+2];
  float wb0 = W1s[o*6+3], wb1 = W1s[o*6+4], wb2 = W1s[o*6+5];
  float pmax = -INFINITY;
  #pragma unroll
  for (int t = 0; t < KNN; ++t)
    pmax = fmaxf(pmax, nbx[pt][t][0]*wa0 + nbx[pt][t][1]*wa1 + nbx[pt][t][2]*wa2);
  float po = nbx[pt][20][0]*wa0 + nbx[pt][20][1]*wa1 + nbx[pt][20][2]*wa2;
  float qo = nbx[pt][20][0]*wb0 + nbx[pt][20][1]*wb1 + nbx[pt][20][2]*wb2;
  float h = pmax - po + qo;
  float sc = bn1s[o] / sqrtf(bn1s[192+o] + 1e-5f);
  h = (h - bn1s[128+o])*sc + bn1s[64+o];
  x1out[(size_t)(g0+pt)*64 + o] = f2bu(lrelu(h));
}

// ---------------- MFMA edgeconv (EC2/EC3): block = 8 points, 4 waves ----------------
// LDS ~28 KB -> 4+ blocks/CU. pt-loop unroll capped at 2 (anti frag-hoist spill).
template<int O_, bool BF, bool PRE>
__global__ __launch_bounds__(256, 4) void k_ec(const int* __restrict__ FLAG,
                    const u16* __restrict__ xin, const u16* __restrict__ idx,
                    const void* __restrict__ W, const void* __restrict__ bn,
                    u16* __restrict__ xout){
  if (FLAG[0] != (BF ? 1 : 0)) return;
  __shared__ __align__(16) u16 ANu[8*24*72];     // 27.6 KB
  __shared__ u16 idxL[8][KNN];
  const int tid = threadIdx.x, wv = tid >> 6, lane = tid & 63;
  const int quad = lane >> 4, n = lane & 15;
  const int g0 = blockIdx.x*8, b = g0 / NN, n0 = g0 - b*NN;

  for (int k = tid; k < 8*KNN; k += 256){
    int pt = k/KNN, t = k - pt*KNN;
    idxL[pt][t] = idx[(size_t)(g0+pt)*KNN + t];
  }
  __syncthreads();
  u32* ANw = (u32*)ANu;
  for (int k = tid; k < 192*32; k += 256){
    int row = k >> 5, pr = k & 31;
    int pt = row/24, r = row - pt*24;
    int m = (r < KNN) ? (int)idxL[pt][r] : (n0 + pt);
    ANw[row*36 + pr] = ((const u32*)(xin + ((size_t)b*NN + m)*64))[pr];
  }
  __syncthreads();

  s8v aself[2];
  #pragma unroll
  for (int kc = 0; kc < 2; ++kc)
    aself[kc] = *(const s8v*)&ANu[((lane&7)*24 + 20)*72 + kc*32 + quad*8];

  for (int tt = wv; tt < O_/16; tt += 4){
    const int o = tt*16 + n;
    s8v bah[2], bal[2];
    f4v accq;
    if (PRE){
      f4v tq = {0.f,0.f,0.f,0.f};
      #pragma unroll
      for (int kc = 0; kc < 2; ++kc){
        s8v bb = *(const s8v*)((const u16*)W + (size_t)o*128 + 64 + kc*32 + quad*8);
        tq = mfma16(aself[kc], bb, tq);
      }
      #pragma unroll
      for (int kc = 0; kc < 2; ++kc)
        bah[kc] = *(const s8v*)((const u16*)W + (size_t)o*128 + kc*32 + quad*8);
      f4v uq = {0.f,0.f,0.f,0.f};
      #pragma unroll
      for (int kc = 0; kc < 2; ++kc)
        uq = mfma16(aself[kc], bah[kc], uq);
      accq = tq - uq;
    } else {
      f4v tq = {0.f,0.f,0.f,0.f};
      {
        s8v bbh[2], bbl[2];
        #pragma unroll
        for (int kc = 0; kc < 2; ++kc)
          loadFragHL<BF>(W, (size_t)o*128 + 64 + kc*32 + quad*8, bbh[kc], bbl[kc]);
        #pragma unroll
        for (int kc = 0; kc < 2; ++kc){
          tq = mfma16(aself[kc], bbh[kc], tq);
          if (!BF) tq = mfma16(aself[kc], bbl[kc], tq);
        }
      }
      #pragma unroll
      for (int kc = 0; kc < 2; ++kc)
        loadFragHL<BF>(W, (size_t)o*128 + kc*32 + quad*8, bah[kc], bal[kc]);
      f4v uq = {0.f,0.f,0.f,0.f};
      #pragma unroll
      for (int kc = 0; kc < 2; ++kc){
        uq = mfma16(aself[kc], bah[kc], uq);
        if (!BF) uq = mfma16(aself[kc], bal[kc], uq);
      }
      accq = tq - uq;
    }
    float g  = wget<BF>(bn, o),        be = wget<BF>(bn, O_+o),
          mu = wget<BF>(bn, 2*O_+o),   va = wget<BF>(bn, 3*O_+o);
    float sc = g / sqrtf(va + 1e-5f);

    #pragma unroll 2
    for (int pt = 0; pt < 8; ++pt){
      s8v a0[2], a1[2];
      #pragma unroll
      for (int kc = 0; kc < 2; ++kc){
        a0[kc] = *(const s8v*)&ANu[(pt*24 + (lane&15))*72 + kc*32 + quad*8];
        a1[kc] = *(const s8v*)&ANu[(pt*24 + 16 + (lane&7))*72 + kc*32 + quad*8];
      }
      f4v c0 = {0.f,0.f,0.f,0.f}, c1 = {0.f,0.f,0.f,0.f};
      #pragma unroll
      for (int kc = 0; kc < 2; ++kc){
        c0 = mfma16(a0[kc], bah[kc], c0);
        c1 = mfma16(a1[kc], bah[kc], c1);
        if (!BF && !PRE){
          c0 = mfma16(a0[kc], bal[kc], c0);
          c1 = mfma16(a1[kc], bal[kc], c1);
        }
      }
      float pm = fmaxf(fmaxf(fmaxf(c0[0],c0[1]), fmaxf(c0[2],c0[3])),
                       fmaxf(fmaxf(c1[0],c1[1]), fmaxf(c1[2],c1[3])));
      pm = fmaxf(pm, __shfl_xor(pm, 16));
      pm = fmaxf(pm, __shfl_xor(pm, 32));
      if (quad == (pt >> 2)){
        float h = pm + accq[pt & 3];
        h = (h - mu)*sc + be;
        xout[(size_t)(g0+pt)*O_ + o] = f2bu(lrelu(h));
      }
    }
  }
}

// ---------------- fused MFMA: x1 + x4 recompute + W5 + BN5 + act + pooling ----------
// PTS=8, 512 threads, LDS ~70 KB -> 2 blocks/CU (4 waves/EU). Unroll caps: anti-spill.
// W5 pooling: shfl_xor(16) only + quad0 atomics (rows 8-15 duplicate points 0-7).
#define PTS 8
template<bool BF, bool PRE>
__global__ __launch_bounds__(512, 4)
void k_w5f(const int* __restrict__ FLAG,
      const float* __restrict__ XT,
      const u16* __restrict__ IDX1, const u16* __restrict__ x2g, const u16* __restrict__ x3g,
      const u16* __restrict__ IDX4,
      const void* __restrict__ W1, const void* __restrict__ bn1,
      const void* __restrict__ W4, const void* __restrict__ bn4,
      const void* __restrict__ W5, const void* __restrict__ bn5,
      u32* __restrict__ hmaxk, float* __restrict__ hsum){
  if (FLAG[0] != (BF ? 1 : 0)) return;
  __shared__ __align__(16) u16 ANu[PTS*24*136];   // 52.2 KB
  __shared__ __align__(16) u16 xsu[PTS*520];      // 8.3 KB
  __shared__ float xtn[PTS][21][3];
  __shared__ u16   idx1L[PTS][KNN], idx4L[PTS][KNN];
  __shared__ float W1s[384], bn1s[256], bn4s[1024];
  const int tid = threadIdx.x, wv = tid >> 6, lane = tid & 63;
  const int quad = lane >> 4, n = lane & 15;
  const int g0 = blockIdx.x*PTS, b = g0 / NN, n0 = g0 - b*NN;

  for (int k = tid; k < PTS*KNN; k += 512){
    int pt = k/KNN, t = k - pt*KNN;
    idx1L[pt][t] = IDX1[(size_t)(g0+pt)*KNN + t];
    idx4L[pt][t] = IDX4[(size_t)(g0+pt)*KNN + t];
  }
  if (tid < 384) W1s[tid] = wget<BF>(W1, tid);
  if (tid < 256) bn1s[tid] = wget<BF>(bn1, tid);
  for (int k = tid; k < 1024; k += 512) bn4s[k] = wget<BF>(bn4, k);
  __syncthreads();

  u32* ANw = (u32*)ANu;
  for (int k = tid; k < PTS*24*64; k += 512){
    int row = k >> 6, pr = k & 63;
    int pt = row/24, r = row - pt*24;
    int m = (r < KNN) ? (int)idx4L[pt][r] : (n0 + pt);
    ANw[(pt*24 + r)*68 + pr] = ((const u32*)(x3g + ((size_t)b*NN + m)*128))[pr];
  }
  for (int k = tid; k < PTS*21*3; k += 512){
    int row = k/3, c = k - row*3;
    int pt = row/21, slot = row - pt*21;
    int m = (slot < KNN) ? (int)idx1L[pt][slot] : (n0 + pt);
    xtn[pt][slot][c] = XT[((size_t)b*NN + m)*3 + c];
  }
  u32* xsw = (u32*)xsu;
  for (int k = tid; k < PTS*32; k += 512){
    int pt = k >> 5, c2 = k & 31;
    xsw[pt*260 + 32 + c2] = ((const u32*)(x2g + (size_t)(g0+pt)*64))[c2];
  }
  for (int k = tid; k < PTS*64; k += 512){
    int pt = k >> 6, c2 = k & 63;
    xsw[pt*260 + 64 + c2] = ((const u32*)(x3g + (size_t)(g0+pt)*128))[c2];
  }
  __syncthreads();

  // x1 recompute -> xsu cols 0..63 (PTS*64 == 512: one element per thread)
  {
    int k = tid;
    int pt = k >> 6, o = k & 63;
    float wa0 = W1s[o*6], wa1 = W1s[o*6+1], wa2 = W1s[o*6+2];
    float wb0 = W1s[o*6+3], wb1 = W1s[o*6+4], wb2 = W1s[o*6+5];
    float pmax = -INFINITY;
    #pragma unroll
    for (int t = 0; t < KNN; ++t)
      pmax = fmaxf(pmax, xtn[pt][t][0]*wa0 + xtn[pt][t][1]*wa1 + xtn[pt][t][2]*wa2);
    float po = xtn[pt][20][0]*wa0 + xtn[pt][20][1]*wa1 + xtn[pt][20][2]*wa2;
    float qo = xtn[pt][20][0]*wb0 + xtn[pt][20][1]*wb1 + xtn[pt][20][2]*wb2;
    float h = pmax - po + qo;
    float sc = bn1s[o] / sqrtf(bn1s[192+o] + 1e-5f);
    h = (h - bn1s[128+o])*sc + bn1s[64+o];
    xsu[pt*520 + o] = f2bu(lrelu(h));
  }

  // ---- x4 via MFMA: 16 out-tiles over 8 waves (2 each) ----
  {
    s8v aself[4];
    #pragma unroll
    for (int kc = 0; kc < 4; ++kc)
      aself[kc] = *(const s8v*)&ANu[((lane&7)*24 + 20)*136 + kc*32 + quad*8];

    #pragma unroll 1
    for (int i = 0; i < 2; ++i){
      const int o0 = (wv*2 + i)*16;
      const size_t wrow = (size_t)(o0 + n)*256;
      s8v bah[4];
      f4v accq;
      {
        f4v tq = {0.f,0.f,0.f,0.f};
        #pragma unroll
        for (int kc = 0; kc < 4; ++kc){
          s8v bb = loadW<BF,PRE>(W4, wrow + 128 + kc*32 + quad*8);
          tq = mfma16(aself[kc], bb, tq);
        }
        #pragma unroll
        for (int kc = 0; kc < 4; ++kc)
          bah[kc] = loadW<BF,PRE>(W4, wrow + kc*32 + quad*8);
        f4v uq = {0.f,0.f,0.f,0.f};
        #pragma unroll
        for (int kc = 0; kc < 4; ++kc)
          uq = mfma16(aself[kc], bah[kc], uq);
        accq = tq - uq;
      }
      #pragma unroll 2
      for (int pt = 0; pt < PTS; ++pt){
        s8v a0[4], a1[4];
        #pragma unroll
        for (int kc = 0; kc < 4; ++kc){
          a0[kc] = *(const s8v*)&ANu[(pt*24 + (lane&15))*136 + kc*32 + quad*8];
          a1[kc] = *(const s8v*)&ANu[(pt*24 + 16 + (lane&7))*136 + kc*32 + quad*8];
        }
        f4v c0 = {0.f,0.f,0.f,0.f}, c1 = {0.f,0.f,0.f,0.f};
        #pragma unroll
        for (int kc = 0; kc < 4; ++kc){
          c0 = mfma16(a0[kc], bah[kc], c0);
          c1 = mfma16(a1[kc], bah[kc], c1);
        }
        float pm = fmaxf(fmaxf(fmaxf(c0[0],c0[1]), fmaxf(c0[2],c0[3])),
                         fmaxf(fmaxf(c1[0],c1[1]), fmaxf(c1[2],c1[3])));
        pm = fmaxf(pm, __shfl_xor(pm, 16));
        pm = fmaxf(pm, __shfl_xor(pm, 32));
        if (quad == (pt >> 2)){
          float h = pm + accq[pt & 3];
          int o = o0 + n;
          float sc = bn4s[o] / sqrtf(bn4s[768+o] + 1e-5f);
          h = (h - bn4s[512+o])*sc + bn4s[256+o];
          xsu[pt*520 + 256 + o] = f2bu(lrelu(h));
        }
      }
    }
  }
  __syncthreads();

  // ---- W5 via MFMA: 64 out-tiles over 8 waves; A rows = 8 pts (dups in rows 8-15) --
  {
    #pragma unroll 1
    for (int i = 0; i < 8; ++i){
      const int o = (wv*8 + i)*16 + n;
      const size_t wrow = (size_t)o * 512;
      f4v acc = {0.f,0.f,0.f,0.f};
      #pragma unroll
      for (int kc = 0; kc < 16; ++kc){
        s8v av = *(const s8v*)&xsu[(lane&7)*520 + kc*32 + quad*8];
        s8v bh = loadW<BF,PRE>(W5, wrow + kc*32 + quad*8);
        acc = mfma16(av, bh, acc);
      }
      float g = wget<BF>(bn5, o), be = wget<BF>(bn5, 1024+o),
            mu = wget<BF>(bn5, 2048+o), va = wget<BF>(bn5, 3072+o);
      float sc = g / sqrtf(va + 1e-5f);
      float lm = -INFINITY, ls = 0.f;
      #pragma unroll
      for (int r = 0; r < 4; ++r){
        float h = (acc[r] - mu)*sc + be;
        h = lrelu(h);
        lm = fmaxf(lm, h); ls += h;
      }
      lm = fmaxf(lm, __shfl_xor(lm, 16));
      ls = ls + __shfl_xor(ls, 16);
      if (quad == 0){                        // rows 0-7 = the 8 real points
        atomicMax(&hmaxk[b*1024 + o], f2key(lm));
        atomicAdd(&hsum[b*1024 + o], ls);
      }
    }
  }
}

// ---------------- head: [max|mean] -> FC512 -> FC256 -> FC40 ------------------------
template<bool BF>
__global__ __launch_bounds__(512) void k_head(const int* __restrict__ FLAG,
                    const u32* __restrict__ hmaxk, const float* __restrict__ hsum,
                    const void* __restrict__ Wl1, const void* __restrict__ bn6,
                    const void* __restrict__ Wl2, const void* __restrict__ bl2,
                    const void* __restrict__ bn7,
                    const void* __restrict__ Wl3, const void* __restrict__ bl3,
                    void* __restrict__ out){
  if (FLAG[0] != (BF ? 1 : 0)) return;
  __shared__ float hc[2048];
  __shared__ float h2s[512];
  __shared__ float h3s[256];
  int b = blockIdx.x, tid = threadIdx.x;
  for (int k = tid; k < 1024; k += 512){
    hc[k]        = key2f(hmaxk[b*1024 + k]);
    hc[1024 + k] = hsum[b*1024 + k] * (1.0f/2048.0f);
  }
  __syncthreads();
  {
    float acc = 0.f;
    for (int cc = 0; cc < 2048; cc += 8){
      float w[8];
      wload8<BF>(Wl1, (size_t)tid*2048 + cc, w);
      #pragma unroll
      for (int u = 0; u < 8; ++u) acc += w[u]*hc[cc+u];
    }
    float g = wget<BF>(bn6, tid), be = wget<BF>(bn6, 512+tid),
          mu = wget<BF>(bn6, 1024+tid), va = wget<BF>(bn6, 1536+tid);
    float sc = g / sqrtf(va + 1e-5f);
    h2s[tid] = lrelu((acc - mu)*sc + be);
  }
  __syncthreads();
  if (tid < 256){
    float acc = 0.f;
    for (int cc = 0; cc < 512; cc += 8){
      float w[8];
      wload8<BF>(Wl2, (size_t)tid*512 + cc, w);
      #pragma unroll
      for (int u = 0; u < 8; ++u) acc += w[u]*h2s[cc+u];
    }
    acc += wget<BF>(bl2, tid);
    float g = wget<BF>(bn7, tid), be = wget<BF>(bn7, 256+tid),
          mu = wget<BF>(bn7, 512+tid), va = wget<BF>(bn7, 768+tid);
    float sc = g / sqrtf(va + 1e-5f);
    h3s[tid] = lrelu((acc - mu)*sc + be);
  }
  __syncthreads();
  if (tid < 40){
    float acc = 0.f;
    for (int cc = 0; cc < 256; cc += 8){
      float w[8];
      wload8<BF>(Wl3, (size_t)tid*256 + cc, w);
      #pragma unroll
      for (int u = 0; u < 8; ++u) acc += w[u]*h3s[cc+u];
    }
    acc += wget<BF>(bl3, tid);
    if (BF) ((u16*)out)[b*40 + tid] = f2bu(acc);
    else    ((float*)out)[b*40 + tid] = acc;
  }
}

extern "C" void kernel_launch(void* const* d_in, const int* in_sizes, int n_in,
                              void* d_out, int out_size, void* d_ws, size_t ws_size,
                              hipStream_t stream){
  const void* x   = d_in[0];
  const void* W1  = d_in[1];
  const void* bn1 = d_in[2];
  const void* W2  = d_in[3];
  const void* bn2 = d_in[4];
  const void* W3  = d_in[5];
  const void* bn3 = d_in[6];
  const void* W4  = d_in[7];
  const void* bn4 = d_in[8];
  const void* W5  = d_in[9];
  const void* bn5 = d_in[10];
  const void* Wl1 = d_in[11];
  const void* bn6 = d_in[12];
  const void* Wl2 = d_in[13];
  const void* bl2 = d_in[14];
  const void* bn7 = d_in[15];
  const void* Wl3 = d_in[16];
  const void* bl3 = d_in[17];

  // ---- workspace layout (bytes); base total 15,859,968 (proven-safe envelope) ------
  char* base = (char*)d_ws;
  int*   FLAG  = (int*)  (base + 0);
  float* XT    = (float*)(base + 256);
  float* SQ    = (float*)(base + 393472);
  u32*   HMAXK = (u32*)  (base + 524544);
  float* HSUM  = (float*)(base + 590080);
  u16*   IDX1  = (u16*)  (base + 655616);
  u16*   IDX   = (u16*)  (base + 1966336);
  u16*   X2    = (u16*)  (base + 3277056);
  u16*   X3    = (u16*)  (base + 7471360);
  u16*   X1    = X3;                            // aliases X3: x1 dead before EC3 writes x3
  // optional pre-converted bf16 weights (guards on ws_size; rounds 13-14 proved fit)
  u16*   W4B   = (u16*)  (base + 15859968);     //   131,072 B
  u16*   W5B   = (u16*)  (base + 15991040);     // 1,048,576 B -> 17,039,616
  u16*   W2B   = (u16*)  (base + 17039616);     //    16,384 B
  u16*   W3B   = (u16*)  (base + 17056000);     //    32,768 B -> 17,088,768
  const bool pre  = (ws_size >= (size_t)17039616);
  const bool pre2 = (ws_size >= (size_t)17088768);

  dim3 knnG1(NN/64, BB);
  dim3 knnGM(NN/16, BB);      // MFMA KNN: 16 queries/block, 4 segments

  k_detect<<<1, 256, 0, stream>>>((const u16*)x, FLAG);

  if (pre){
    k_wconv<<<(65536 + 255)/256, 256, 0, stream>>>(FLAG, W4, W4B, 65536);
    k_wconv<<<(524288 + 255)/256, 256, 0, stream>>>(FLAG, W5, W5B, 524288);
  }
  if (pre2){
    k_wconv<<<(8192 + 255)/256, 256, 0, stream>>>(FLAG, W2, W2B, 8192);
    k_wconv<<<(16384 + 255)/256, 256, 0, stream>>>(FLAG, W3, W3B, 16384);
  }

  k_prep<true ><<<PP/256, 256, 0, stream>>>(FLAG, x, XT, SQ, HMAXK, HSUM);
  k_prep<false><<<PP/256, 256, 0, stream>>>(FLAG, x, XT, SQ, HMAXK, HSUM);

  // EC1: XT (C=3) -> x1
  k_knn<3,128><<<knnG1, 256, 0, stream>>>(XT, SQ, IDX1);
  k_ec1<true ><<<PP/4, 256, 0, stream>>>(FLAG, XT, IDX1, W1, bn1, X1);
  k_ec1<false><<<PP/4, 256, 0, stream>>>(FLAG, XT, IDX1, W1, bn1, X1);

  // EC2: x1 -> x2 (MFMA edgeconv)
  k_sq<64><<<PP/256, 256, 0, stream>>>(X1, SQ);
  k_knn_mfma<64><<<knnGM, 256, 0, stream>>>(X1, SQ, IDX);
  if (pre2){
    k_ec<64,true ,true ><<<PP/8, 256, 0, stream>>>(FLAG, X1, IDX, W2B, bn2, X2);
    k_ec<64,false,true ><<<PP/8, 256, 0, stream>>>(FLAG, X1, IDX, W2B, bn2, X2);
  } else {
    k_ec<64,true ,false><<<PP/8, 256, 0, stream>>>(FLAG, X1, IDX, W2, bn2, X2);
    k_ec<64,false,false><<<PP/8, 256, 0, stream>>>(FLAG, X1, IDX, W2, bn2, X2);
  }

  // EC3: x2 -> x3 (overwrites x1 region)
  k_sq<64><<<PP/256, 256, 0, stream>>>(X2, SQ);
  k_knn_mfma<64><<<knnGM, 256, 0, stream>>>(X2, SQ, IDX);
  if (pre2){
    k_ec<128,true ,true ><<<PP/8, 256, 0, stream>>>(FLAG, X2, IDX, W3B, bn3, X3);
    k_ec<128,false,true ><<<PP/8, 256, 0, stream>>>(FLAG, X2, IDX, W3B, bn3, X3);
  } else {
    k_ec<128,true ,false><<<PP/8, 256, 0, stream>>>(FLAG, X2, IDX, W3, bn3, X3);
    k_ec<128,false,false><<<PP/8, 256, 0, stream>>>(FLAG, X2, IDX, W3, bn3, X3);
  }

  // EC4 KNN only (x4 recomputed inside k_w5f)
  k_sq<128><<<PP/256, 256, 0, stream>>>(X3, SQ);
  k_knn_mfma<128><<<knnGM, 256, 0, stream>>>(X3, SQ, IDX);

  // fused x1/x4 recompute + W5 + bn5 + act + global max/mean pooling (PTS=8)
  if (pre){
    k_w5f<true ,true ><<<PP/PTS, 512, 0, stream>>>(FLAG, XT, IDX1, X2, X3, IDX,
                                                   W1, bn1, W4B, bn4, W5B, bn5, HMAXK, HSUM);
    k_w5f<false,true ><<<PP/PTS, 512, 0, stream>>>(FLAG, XT, IDX1, X2, X3, IDX,
                                                   W1, bn1, W4B, bn4, W5B, bn5, HMAXK, HSUM);
  } else {
    k_w5f<true ,false><<<PP/PTS, 512, 0, stream>>>(FLAG, XT, IDX1, X2, X3, IDX,
                                                   W1, bn1, W4, bn4, W5, bn5, HMAXK, HSUM);
    k_w5f<false,false><<<PP/PTS, 512, 0, stream>>>(FLAG, XT, IDX1, X2, X3, IDX,
                                                   W1, bn1, W4, bn4, W5, bn5, HMAXK, HSUM);
  }

  // head FCs
  k_head<true ><<<BB, 512, 0, stream>>>(FLAG, HMAXK, HSUM, Wl1, bn6, Wl2, bl2, bn7, Wl3, bl3, d_out);
  k_head<false><<<BB, 512, 0, stream>>>(FLAG, HMAXK, HSUM, Wl1, bn6, Wl2, bl2, bn7, Wl3, bl3, d_out);
}

// Round 16
// 1646.392 us; speedup vs baseline: 1.0757x; 1.0757x over previous
//
#include <hip/hip_runtime.h>
#include <hip/hip_bf16.h>

#define BB 16
#define NN 2048
#define PP (BB*NN)
#define KNN 20

typedef __hip_bfloat16 bf16;
typedef unsigned short u16;
typedef unsigned int u32;
typedef __attribute__((ext_vector_type(8))) short s8v;   // 8 bf16 = 4 VGPR (MFMA A/B frag)
typedef __attribute__((ext_vector_type(4))) float f4v;   // MFMA C/D frag

__device__ __forceinline__ float bu2f(u16 u){ return __uint_as_float(((u32)u) << 16); }
__device__ __forceinline__ float lo16(u32 u){ return __uint_as_float(u << 16); }
__device__ __forceinline__ float hi16(u32 u){ return __uint_as_float(u & 0xffff0000u); }
__device__ __forceinline__ u16 f2bu(float f){ bf16 h = __float2bfloat16(f); return *(u16*)&h; }
__device__ __forceinline__ float lrelu(float h){ return (h >= 0.f) ? h : 0.2f*h; }

__device__ __forceinline__ u32 f2key(float f){
  u32 u = __float_as_uint(f);
  return (u & 0x80000000u) ? ~u : (u | 0x80000000u);
}
__device__ __forceinline__ float key2f(u32 k){
  u32 u = (k & 0x80000000u) ? (k & 0x7FFFFFFFu) : ~k;
  return __uint_as_float(u);
}

template<bool BF> __device__ __forceinline__ float wget(const void* p, size_t i){
  return BF ? bu2f(((const u16*)p)[i]) : ((const float*)p)[i];
}
template<bool BF> __device__ __forceinline__ void wload8(const void* p, size_t base, float w[8]){
  if (BF){
    const uint4 u = *(const uint4*)((const u16*)p + base);
    w[0]=lo16(u.x); w[1]=hi16(u.x); w[2]=lo16(u.y); w[3]=hi16(u.y);
    w[4]=lo16(u.z); w[5]=hi16(u.z); w[6]=lo16(u.w); w[7]=hi16(u.w);
  } else {
    const float4* f = (const float4*)((const float*)p + base);
    float4 a = f[0], b = f[1];
    w[0]=a.x; w[1]=a.y; w[2]=a.z; w[3]=a.w; w[4]=b.x; w[5]=b.y; w[6]=b.z; w[7]=b.w;
  }
}

__device__ __forceinline__ f4v mfma16(s8v a, s8v b, f4v c){
  return __builtin_amdgcn_mfma_f32_16x16x32_bf16(a, b, c, 0, 0, 0);
}

// load 8 weights as hi/lo bf16 fragments (lo = residual; exact-weight MFMA via 2 ops)
template<bool BF> __device__ __forceinline__ void loadFragHL(const void* p, size_t base,
                                                             s8v& hi, s8v& lo){
  if (BF){
    hi = *(const s8v*)((const u16*)p + base);
  } else {
    float w[8]; wload8<false>(p, base, w);
    #pragma unroll
    for (int i = 0; i < 8; ++i){
      u16 hb = f2bu(w[i]);
      hi[i] = (short)hb;
      lo[i] = (short)f2bu(w[i] - bu2f(hb));
    }
  }
}
// load 8 weights rounded to bf16 (single-frag)
template<bool BF> __device__ __forceinline__ s8v loadFragR(const void* p, size_t base){
  if (BF){
    return *(const s8v*)((const u16*)p + base);
  } else {
    float w[8]; wload8<false>(p, base, w);
    s8v r;
    #pragma unroll
    for (int i = 0; i < 8; ++i) r[i] = (short)f2bu(w[i]);
    return r;
  }
}
// weight frag: PRE -> pre-converted bf16 in ws; else rounded on the fly
template<bool BF, bool PRE> __device__ __forceinline__ s8v loadW(const void* p, size_t base){
  if (PRE) return *(const s8v*)((const u16*)p + base);
  else     return loadFragR<BF>(p, base);
}

// register-resident sorted (descending) top-20 insert, value+index pair (stage-1 KNN).
__device__ __forceinline__ void topk_ins(float d, u32 id, float (&tv)[KNN], u32 (&ti)[KNN]){
  float pv = 0.f; u32 pi = 0u; bool cp = false;
  #pragma unroll
  for (int t = 0; t < KNN; ++t){
    bool c = (tv[t] < d);
    float ov = tv[t]; u32 oi = ti[t];
    tv[t] = c ? (cp ? pv : d) : tv[t];
    ti[t] = c ? (cp ? pi : id) : ti[t];
    pv = ov; pi = oi; cp = c;
  }
}
// packed-key insert: key = (f2key(d) & ~0x7FF) | (2047-idx) — orders by (distance,
// smaller-index) = top_k stable tie rule.
__device__ __forceinline__ void topk_insp(u32 pk, u32 (&tv)[KNN]){
  u32 pv = 0u; bool cp = false;
  #pragma unroll
  for (int t = 0; t < KNN; ++t){
    bool c = (tv[t] < pk);
    u32 ov = tv[t];
    tv[t] = c ? (cp ? pv : pk) : tv[t];
    pv = ov; cp = c;
  }
}

// ---------------- dtype detector: bf16 (1) vs fp32 (0) ------------------------------
__global__ void k_detect(const u16* __restrict__ xr, int* __restrict__ flag){
  __shared__ int cnt;
  if (threadIdx.x == 0) cnt = 0;
  __syncthreads();
  float v = bu2f(xr[threadIdx.x * 2]);
  float a = fabsf(v);
  int ok = (a > 1e-6f && a < 1e6f) ? 1 : 0;
  atomicAdd(&cnt, ok);
  __syncthreads();
  if (threadIdx.x == 0) flag[0] = (cnt >= 160) ? 1 : 0;
}

// ---------------- weight -> bf16 pre-conversion -------------------------------------
__global__ void k_wconv(const int* __restrict__ FLAG, const void* __restrict__ src,
                        u16* __restrict__ dst, int n){
  int i = blockIdx.x*256 + threadIdx.x;
  if (i >= n) return;
  dst[i] = FLAG[0] ? ((const u16*)src)[i] : f2bu(((const float*)src)[i]);
}

// ---------------- prep: transpose x [B,3,N] -> XT [P,3] fp32, SQ, pool init ---------
template<bool BF>
__global__ void k_prep(const int* __restrict__ FLAG, const void* __restrict__ x,
                       float* __restrict__ XT, float* __restrict__ SQ,
                       u32* __restrict__ hmaxk, float* __restrict__ hsum){
  if (FLAG[0] != (BF ? 1 : 0)) return;
  int i = blockIdx.x*256 + threadIdx.x;
  if (i >= PP) return;
  int b = i / NN, n = i - b*NN;
  float s = 0.f;
  #pragma unroll
  for (int c = 0; c < 3; ++c){
    float v = wget<BF>(x, ((size_t)b*3 + c)*NN + n);
    XT[(size_t)i*3 + c] = v;
    s += v*v;
  }
  SQ[i] = s;
  if (i < BB*1024){ hmaxk[i] = 0u; hsum[i] = 0.f; }
}

// ---------------- SQ[i] = sum_c x[i,c]^2 -------------------------------------------
template<int Cin>
__global__ void k_sq(const u16* __restrict__ xin, float* __restrict__ SQ){
  int i = blockIdx.x*256 + threadIdx.x;
  if (i >= PP) return;
  const u32* r = (const u32*)(xin + (size_t)i*Cin);
  float s = 0.f;
  for (int c = 0; c < Cin/2; ++c){
    u32 u = r[c];
    float a = lo16(u), b = hi16(u);
    s += a*a; s += b*b;
  }
  SQ[i] = s;
}

// ---------------- stage-1 KNN (C=3 fp32): exact value+index (feeds x1 twice) --------
template<int C, int TC>
__global__ __launch_bounds__(256) void k_knn(const float* __restrict__ xin,
                                             const float* __restrict__ SQ,
                                             u16* __restrict__ IDX){
  __shared__ float cf[4][TC*C];
  __shared__ float csqv[4][TC];
  __shared__ float tvL[4][KNN][64];
  __shared__ u16   tiL[4][KNN][64];
  const int tid = threadIdx.x, w = tid >> 6, lane = tid & 63;
  const int b = blockIdx.y;
  const int q = blockIdx.x*64 + lane;
  const int j0 = w * 512;

  float qf[C];
  const float* xq = xin + ((size_t)b*NN + q)*C;
  #pragma unroll
  for (int c = 0; c < C; ++c) qf[c] = xq[c];
  const float sqq = SQ[b*NN + q];

  float tv[KNN]; u32 ti[KNN];
  #pragma unroll
  for (int t = 0; t < KNN; ++t){ tv[t] = -INFINITY; ti[t] = 0; }

  for (int t0 = 0; t0 < 512; t0 += TC){
    __syncthreads();
    const float* src = xin + ((size_t)b*NN + j0 + t0)*C;
    for (int k = lane; k < TC*C; k += 64) cf[w][k] = src[k];
    for (int k = lane; k < TC; k += 64) csqv[w][k] = SQ[b*NN + j0 + t0 + k];
    __syncthreads();
    for (int j = 0; j < TC; ++j){
      float dot = 0.f;
      #pragma unroll
      for (int c = 0; c < C; ++c) dot += qf[c]*cf[w][j*C + c];
      float d = 2.f*dot - sqq - csqv[w][j];
      if (d > tv[KNN-1]) topk_ins(d, (u32)(j0 + t0 + j), tv, ti);
    }
  }
  #pragma unroll
  for (int t = 0; t < KNN; ++t){ tvL[w][t][lane] = tv[t]; tiL[w][t][lane] = (u16)ti[t]; }
  __syncthreads();
  if (tid < 64){
    int p0=0,p1=0,p2=0,p3=0;
    u16* op = IDX + ((size_t)b*NN + q)*KNN;
    for (int t = 0; t < KNN; ++t){
      float v0 = tvL[0][p0][tid], v1 = tvL[1][p1][tid], v2 = tvL[2][p2][tid], v3 = tvL[3][p3][tid];
      int bs = 0; float bv = v0;
      if (v1 > bv){ bv = v1; bs = 1; }
      if (v2 > bv){ bv = v2; bs = 2; }
      if (v3 > bv){ bv = v3; bs = 3; }
      u16 bi;
      if      (bs == 0){ bi = tiL[0][p0][tid]; p0++; }
      else if (bs == 1){ bi = tiL[1][p1][tid]; p1++; }
      else if (bs == 2){ bi = tiL[2][p2][tid]; p2++; }
      else             { bi = tiL[3][p3][tid]; p3++; }
      op[t] = bi;
    }
  }
}

// ---------------- MFMA KNN (stages 2-4): packed-key top-20 --------------------------
// Block = 16 queries x 4 seg-waves (512 candidates each) -> 2048 blocks (8/CU).
template<int C>
__global__ __launch_bounds__(256) void k_knn_mfma(const u16* __restrict__ xin,
                                                  const float* __restrict__ SQ,
                                                  u16* __restrict__ IDX){
  __shared__ u32 tvL[KNN][256];        // 20 KB
  const int tid = threadIdx.x, w = tid >> 6, lane = tid & 63;
  const int quad = lane >> 4, n = lane & 15;
  const int b = blockIdx.y;
  const int q = blockIdx.x*16 + n;
  const int cbase = w * 512;           // this wave's candidate segment
  const u16* Xb = xin + (size_t)b*NN*C;

  s8v bfrag[C/32];
  #pragma unroll
  for (int kc = 0; kc < C/32; ++kc)
    bfrag[kc] = *(const s8v*)(Xb + (size_t)q*C + kc*32 + quad*8);
  const float sqq = SQ[b*NN + q];

  u32 tv[KNN];
  #pragma unroll
  for (int t = 0; t < KNN; ++t) tv[t] = 0u;

  s8v afr[C/32], afn[C/32];
  #pragma unroll
  for (int kc = 0; kc < C/32; ++kc)
    afr[kc] = *(const s8v*)(Xb + (size_t)(cbase + n)*C + kc*32 + quad*8);

  for (int ct = cbase; ct < cbase + 512; ct += 16){
    int ctn = (ct + 16 < cbase + 512) ? (ct + 16) : cbase;
    #pragma unroll
    for (int kc = 0; kc < C/32; ++kc)
      afn[kc] = *(const s8v*)(Xb + (size_t)(ctn + n)*C + kc*32 + quad*8);
    f4v sqc = *(const f4v*)&SQ[b*NN + ct + quad*4];
    f4v acc = {0.f, 0.f, 0.f, 0.f};
    #pragma unroll
    for (int kc = 0; kc < C/32; ++kc)
      acc = mfma16(afr[kc], bfrag[kc], acc);
    #pragma unroll
    for (int r = 0; r < 4; ++r){
      float d = 2.f*acc[r] - sqq - sqc[r];
      u32 pk = (f2key(d) & 0xFFFFF800u) | (2047u - (u32)(ct + quad*4 + r));
      if (pk > tv[KNN-1]) topk_insp(pk, tv);
    }
    #pragma unroll
    for (int kc = 0; kc < C/32; ++kc) afr[kc] = afn[kc];
  }
  #pragma unroll
  for (int t = 0; t < KNN; ++t) tvL[t][tid] = tv[t];
  __syncthreads();

  if (tid < 16){                        // 16-way merge (4 segs x 4 quads), keys unique
    int mq = blockIdx.x*16 + tid;
    int p[16];
    #pragma unroll
    for (int s = 0; s < 16; ++s) p[s] = 0;
    u16* op = IDX + ((size_t)b*NN + mq)*KNN;
    for (int t = 0; t < KNN; ++t){
      u32 bv = 0u; int bs = 0;
      #pragma unroll
      for (int s = 0; s < 16; ++s){
        int col = (s >> 2)*64 + (s & 3)*16 + tid;   // wave (s>>2), quad (s&3)
        u32 v = tvL[p[s]][col];
        if (v > bv){ bv = v; bs = s; }
      }
      op[t] = (u16)(2047u - (bv & 2047u)); p[bs]++;
    }
  }
}

// ---------------- EC1 direct (C=3 -> O=64): block = 4 points x 64 channels ----------
template<bool BF>
__global__ __launch_bounds__(256) void k_ec1(const int* __restrict__ FLAG,
                    const float* __restrict__ XT,
                    const u16* __restrict__ IDX1, const void* __restrict__ W1,
                    const void* __restrict__ bn1, u16* __restrict__ x1out){
  if (FLAG[0] != (BF ? 1 : 0)) return;
  __shared__ float nbx[4][21][3];
  __shared__ float W1s[384];
  __shared__ float bn1s[256];
  __shared__ u16   idxL[4][KNN];
  const int tid = threadIdx.x;
  const int g0 = blockIdx.x*4, b = g0 / NN;
  for (int k = tid; k < 384; k += 256) W1s[k] = wget<BF>(W1, k);
  if (tid < 256) bn1s[tid] = wget<BF>(bn1, tid);
  if (tid < 80){ int pt = tid/KNN, t = tid%KNN; idxL[pt][t] = IDX1[(size_t)(g0+pt)*KNN + t]; }
  __syncthreads();
  for (int k = tid; k < 4*21*3; k += 256){
    int row = k/3, c = k - row*3;
    int pt = row/21, slot = row - pt*21;
    int m = (slot < KNN) ? (int)idxL[pt][slot] : (g0 + pt - b*NN);
    nbx[pt][slot][c] = XT[((size_t)b*NN + m)*3 + c];
  }
  __syncthreads();
  int pt = tid >> 6, o = tid & 63;
  float wa0 = W1s[o*6], wa1 = W1s[o*6+1], wa2 = W1s[o*6+2];
  float wb0 = W1s[o*6+3], wb1 = W1s[o*6+4], wb2 = W1s[o*6+5];
  float pmax = -INFINITY;
  #pragma unroll
  for (int t = 0; t < KNN; ++t)
    pmax = fmaxf(pmax, nbx[pt][t][0]*wa0 + nbx[pt][t][1]*wa1 + nbx[pt][t][2]*wa2);
  float po = nbx[pt][20][0]*wa0 + nbx[pt][20][1]*wa1 + nbx[pt][20][2]*wa2;
  float qo = nbx[pt][20][0]*wb0 + nbx[pt][20][1]*wb1 + nbx[pt][20][2]*wb2;
  float h = pmax - po + qo;
  float sc = bn1s[o] / sqrtf(bn1s[192+o] + 1e-5f);
  h = (h - bn1s[128+o])*sc + bn1s[64+o];
  x1out[(size_t)(g0+pt)*64 + o] = f2bu(lrelu(h));
}

// ---------------- MFMA edgeconv (EC2/EC3): block = 8 points, 4 waves ----------------
// LDS ~28 KB -> 4+ blocks/CU. pt-loop unroll capped at 2 (anti frag-hoist spill).
template<int O_, bool BF, bool PRE>
__global__ __launch_bounds__(256, 4) void k_ec(const int* __restrict__ FLAG,
                    const u16* __restrict__ xin, const u16* __restrict__ idx,
                    const void* __restrict__ W, const void* __restrict__ bn,
                    u16* __restrict__ xout){
  if (FLAG[0] != (BF ? 1 : 0)) return;
  __shared__ __align__(16) u16 ANu[8*24*72];     // 27.6 KB
  __shared__ u16 idxL[8][KNN];
  const int tid = threadIdx.x, wv = tid >> 6, lane = tid & 63;
  const int quad = lane >> 4, n = lane & 15;
  const int g0 = blockIdx.x*8, b = g0 / NN, n0 = g0 - b*NN;

  for (int k = tid; k < 8*KNN; k += 256){
    int pt = k/KNN, t = k - pt*KNN;
    idxL[pt][t] = idx[(size_t)(g0+pt)*KNN + t];
  }
  __syncthreads();
  u32* ANw = (u32*)ANu;
  for (int k = tid; k < 192*32; k += 256){
    int row = k >> 5, pr = k & 31;
    int pt = row/24, r = row - pt*24;
    int m = (r < KNN) ? (int)idxL[pt][r] : (n0 + pt);
    ANw[row*36 + pr] = ((const u32*)(xin + ((size_t)b*NN + m)*64))[pr];
  }
  __syncthreads();

  s8v aself[2];
  #pragma unroll
  for (int kc = 0; kc < 2; ++kc)
    aself[kc] = *(const s8v*)&ANu[((lane&7)*24 + 20)*72 + kc*32 + quad*8];

  for (int tt = wv; tt < O_/16; tt += 4){
    const int o = tt*16 + n;
    s8v bah[2], bal[2];
    f4v accq;
    if (PRE){
      f4v tq = {0.f,0.f,0.f,0.f};
      #pragma unroll
      for (int kc = 0; kc < 2; ++kc){
        s8v bb = *(const s8v*)((const u16*)W + (size_t)o*128 + 64 + kc*32 + quad*8);
        tq = mfma16(aself[kc], bb, tq);
      }
      #pragma unroll
      for (int kc = 0; kc < 2; ++kc)
        bah[kc] = *(const s8v*)((const u16*)W + (size_t)o*128 + kc*32 + quad*8);
      f4v uq = {0.f,0.f,0.f,0.f};
      #pragma unroll
      for (int kc = 0; kc < 2; ++kc)
        uq = mfma16(aself[kc], bah[kc], uq);
      accq = tq - uq;
    } else {
      f4v tq = {0.f,0.f,0.f,0.f};
      {
        s8v bbh[2], bbl[2];
        #pragma unroll
        for (int kc = 0; kc < 2; ++kc)
          loadFragHL<BF>(W, (size_t)o*128 + 64 + kc*32 + quad*8, bbh[kc], bbl[kc]);
        #pragma unroll
        for (int kc = 0; kc < 2; ++kc){
          tq = mfma16(aself[kc], bbh[kc], tq);
          if (!BF) tq = mfma16(aself[kc], bbl[kc], tq);
        }
      }
      #pragma unroll
      for (int kc = 0; kc < 2; ++kc)
        loadFragHL<BF>(W, (size_t)o*128 + kc*32 + quad*8, bah[kc], bal[kc]);
      f4v uq = {0.f,0.f,0.f,0.f};
      #pragma unroll
      for (int kc = 0; kc < 2; ++kc){
        uq = mfma16(aself[kc], bah[kc], uq);
        if (!BF) uq = mfma16(aself[kc], bal[kc], uq);
      }
      accq = tq - uq;
    }
    float g  = wget<BF>(bn, o),        be = wget<BF>(bn, O_+o),
          mu = wget<BF>(bn, 2*O_+o),   va = wget<BF>(bn, 3*O_+o);
    float sc = g / sqrtf(va + 1e-5f);

    #pragma unroll 2
    for (int pt = 0; pt < 8; ++pt){
      s8v a0[2], a1[2];
      #pragma unroll
      for (int kc = 0; kc < 2; ++kc){
        a0[kc] = *(const s8v*)&ANu[(pt*24 + (lane&15))*72 + kc*32 + quad*8];
        a1[kc] = *(const s8v*)&ANu[(pt*24 + 16 + (lane&7))*72 + kc*32 + quad*8];
      }
      f4v c0 = {0.f,0.f,0.f,0.f}, c1 = {0.f,0.f,0.f,0.f};
      #pragma unroll
      for (int kc = 0; kc < 2; ++kc){
        c0 = mfma16(a0[kc], bah[kc], c0);
        c1 = mfma16(a1[kc], bah[kc], c1);
        if (!BF && !PRE){
          c0 = mfma16(a0[kc], bal[kc], c0);
          c1 = mfma16(a1[kc], bal[kc], c1);
        }
      }
      float pm = fmaxf(fmaxf(fmaxf(c0[0],c0[1]), fmaxf(c0[2],c0[3])),
                       fmaxf(fmaxf(c1[0],c1[1]), fmaxf(c1[2],c1[3])));
      pm = fmaxf(pm, __shfl_xor(pm, 16));
      pm = fmaxf(pm, __shfl_xor(pm, 32));
      if (quad == (pt >> 2)){
        float h = pm + accq[pt & 3];
        h = (h - mu)*sc + be;
        xout[(size_t)(g0+pt)*O_ + o] = f2bu(lrelu(h));
      }
    }
  }
}

// ---------------- fused MFMA: x1 + x4 recompute + W5 + BN5 + act + pooling ----------
// PTS=16, 512 threads (round-14 proven config: 0.52 ms; PTS=8 regressed to 0.65).
#define PTS 16
template<bool BF, bool PRE>
__global__ __launch_bounds__(512, 1)
void k_w5f(const int* __restrict__ FLAG,
      const float* __restrict__ XT,
      const u16* __restrict__ IDX1, const u16* __restrict__ x2g, const u16* __restrict__ x3g,
      const u16* __restrict__ IDX4,
      const void* __restrict__ W1, const void* __restrict__ bn1,
      const void* __restrict__ W4, const void* __restrict__ bn4,
      const void* __restrict__ W5, const void* __restrict__ bn5,
      u32* __restrict__ hmaxk, float* __restrict__ hsum){
  if (FLAG[0] != (BF ? 1 : 0)) return;
  __shared__ __align__(16) u16 ANu[PTS*24*136];   // 104.4 KB
  __shared__ __align__(16) u16 xsu[PTS*520];      // 16.6 KB
  __shared__ float xtn[PTS][21][3];
  __shared__ u16   idx1L[PTS][KNN], idx4L[PTS][KNN];
  __shared__ float W1s[384], bn1s[256], bn4s[1024];
  const int tid = threadIdx.x, wv = tid >> 6, lane = tid & 63;
  const int quad = lane >> 4, n = lane & 15;
  const int g0 = blockIdx.x*PTS, b = g0 / NN, n0 = g0 - b*NN;

  for (int k = tid; k < PTS*KNN; k += 512){
    int pt = k/KNN, t = k - pt*KNN;
    idx1L[pt][t] = IDX1[(size_t)(g0+pt)*KNN + t];
    idx4L[pt][t] = IDX4[(size_t)(g0+pt)*KNN + t];
  }
  if (tid < 384) W1s[tid] = wget<BF>(W1, tid);
  if (tid < 256) bn1s[tid] = wget<BF>(bn1, tid);
  for (int k = tid; k < 1024; k += 512) bn4s[k] = wget<BF>(bn4, k);
  __syncthreads();

  u32* ANw = (u32*)ANu;
  for (int k = tid; k < PTS*24*64; k += 512){
    int row = k >> 6, pr = k & 63;
    int pt = row/24, r = row - pt*24;
    int m = (r < KNN) ? (int)idx4L[pt][r] : (n0 + pt);
    ANw[(pt*24 + r)*68 + pr] = ((const u32*)(x3g + ((size_t)b*NN + m)*128))[pr];
  }
  for (int k = tid; k < PTS*21*3; k += 512){
    int row = k/3, c = k - row*3;
    int pt = row/21, slot = row - pt*21;
    int m = (slot < KNN) ? (int)idx1L[pt][slot] : (n0 + pt);
    xtn[pt][slot][c] = XT[((size_t)b*NN + m)*3 + c];
  }
  u32* xsw = (u32*)xsu;
  for (int k = tid; k < PTS*32; k += 512){
    int pt = k >> 5, c2 = k & 31;
    xsw[pt*260 + 32 + c2] = ((const u32*)(x2g + (size_t)(g0+pt)*64))[c2];
  }
  for (int k = tid; k < PTS*64; k += 512){
    int pt = k >> 6, c2 = k & 63;
    xsw[pt*260 + 64 + c2] = ((const u32*)(x3g + (size_t)(g0+pt)*128))[c2];
  }
  __syncthreads();

  // x1 recompute -> xsu cols 0..63
  #pragma unroll
  for (int hh = 0; hh < PTS*64/512; ++hh){
    int k = tid + hh*512;
    int pt = k >> 6, o = k & 63;
    float wa0 = W1s[o*6], wa1 = W1s[o*6+1], wa2 = W1s[o*6+2];
    float wb0 = W1s[o*6+3], wb1 = W1s[o*6+4], wb2 = W1s[o*6+5];
    float pmax = -INFINITY;
    #pragma unroll
    for (int t = 0; t < KNN; ++t)
      pmax = fmaxf(pmax, xtn[pt][t][0]*wa0 + xtn[pt][t][1]*wa1 + xtn[pt][t][2]*wa2);
    float po = xtn[pt][20][0]*wa0 + xtn[pt][20][1]*wa1 + xtn[pt][20][2]*wa2;
    float qo = xtn[pt][20][0]*wb0 + xtn[pt][20][1]*wb1 + xtn[pt][20][2]*wb2;
    float h = pmax - po + qo;
    float sc = bn1s[o] / sqrtf(bn1s[192+o] + 1e-5f);
    h = (h - bn1s[128+o])*sc + bn1s[64+o];
    xsu[pt*520 + o] = f2bu(lrelu(h));
  }

  // ---- x4 via MFMA: 16 out-tiles over 8 waves (2 each) ----
  {
    s8v aself[4];
    #pragma unroll
    for (int kc = 0; kc < 4; ++kc)
      aself[kc] = *(const s8v*)&ANu[((lane&15)*24 + 20)*136 + kc*32 + quad*8];

    #pragma unroll 1
    for (int i = 0; i < 2; ++i){
      const int o0 = (wv*2 + i)*16;
      const size_t wrow = (size_t)(o0 + n)*256;
      s8v bah[4];
      f4v accq;
      {
        f4v tq = {0.f,0.f,0.f,0.f};
        #pragma unroll
        for (int kc = 0; kc < 4; ++kc){
          s8v bb = loadW<BF,PRE>(W4, wrow + 128 + kc*32 + quad*8);
          tq = mfma16(aself[kc], bb, tq);
        }
        #pragma unroll
        for (int kc = 0; kc < 4; ++kc)
          bah[kc] = loadW<BF,PRE>(W4, wrow + kc*32 + quad*8);
        f4v uq = {0.f,0.f,0.f,0.f};
        #pragma unroll
        for (int kc = 0; kc < 4; ++kc)
          uq = mfma16(aself[kc], bah[kc], uq);
        accq = tq - uq;
      }
      #pragma unroll 2
      for (int pt = 0; pt < PTS; ++pt){
        s8v a0[4], a1[4];
        #pragma unroll
        for (int kc = 0; kc < 4; ++kc){
          a0[kc] = *(const s8v*)&ANu[(pt*24 + (lane&15))*136 + kc*32 + quad*8];
          a1[kc] = *(const s8v*)&ANu[(pt*24 + 16 + (lane&7))*136 + kc*32 + quad*8];
        }
        f4v c0 = {0.f,0.f,0.f,0.f}, c1 = {0.f,0.f,0.f,0.f};
        #pragma unroll
        for (int kc = 0; kc < 4; ++kc){
          c0 = mfma16(a0[kc], bah[kc], c0);
          c1 = mfma16(a1[kc], bah[kc], c1);
        }
        float pm = fmaxf(fmaxf(fmaxf(c0[0],c0[1]), fmaxf(c0[2],c0[3])),
                         fmaxf(fmaxf(c1[0],c1[1]), fmaxf(c1[2],c1[3])));
        pm = fmaxf(pm, __shfl_xor(pm, 16));
        pm = fmaxf(pm, __shfl_xor(pm, 32));
        if (quad == (pt >> 2)){
          float h = pm + accq[pt & 3];
          int o = o0 + n;
          float sc = bn4s[o] / sqrtf(bn4s[768+o] + 1e-5f);
          h = (h - bn4s[512+o])*sc + bn4s[256+o];
          xsu[pt*520 + 256 + o] = f2bu(lrelu(h));
        }
      }
    }
  }
  __syncthreads();

  // ---- W5 via MFMA: 64 out-tiles over 8 waves (8 each); A rows = 16 points ----
  {
    #pragma unroll 1
    for (int i = 0; i < 8; ++i){
      const int o = (wv*8 + i)*16 + n;
      const size_t wrow = (size_t)o * 512;
      f4v acc = {0.f,0.f,0.f,0.f};
      #pragma unroll
      for (int kc = 0; kc < 16; ++kc){
        s8v av = *(const s8v*)&xsu[(lane&15)*520 + kc*32 + quad*8];
        s8v bh = loadW<BF,PRE>(W5, wrow + kc*32 + quad*8);
        acc = mfma16(av, bh, acc);
      }
      float g = wget<BF>(bn5, o), be = wget<BF>(bn5, 1024+o),
            mu = wget<BF>(bn5, 2048+o), va = wget<BF>(bn5, 3072+o);
      float sc = g / sqrtf(va + 1e-5f);
      float lm = -INFINITY, ls = 0.f;
      #pragma unroll
      for (int r = 0; r < 4; ++r){
        float h = (acc[r] - mu)*sc + be;
        h = lrelu(h);
        lm = fmaxf(lm, h); ls += h;
      }
      lm = fmaxf(lm, __shfl_xor(lm, 16));
      ls = ls + __shfl_xor(ls, 16);
      lm = fmaxf(lm, __shfl_xor(lm, 32));
      ls = ls + __shfl_xor(ls, 32);
      if (quad == 0){
        atomicMax(&hmaxk[b*1024 + o], f2key(lm));
        atomicAdd(&hsum[b*1024 + o], ls);
      }
    }
  }
}

// ---------------- head: [max|mean] -> FC512 -> FC256 -> FC40 ------------------------
template<bool BF>
__global__ __launch_bounds__(512) void k_head(const int* __restrict__ FLAG,
                    const u32* __restrict__ hmaxk, const float* __restrict__ hsum,
                    const void* __restrict__ Wl1, const void* __restrict__ bn6,
                    const void* __restrict__ Wl2, const void* __restrict__ bl2,
                    const void* __restrict__ bn7,
                    const void* __restrict__ Wl3, const void* __restrict__ bl3,
                    void* __restrict__ out){
  if (FLAG[0] != (BF ? 1 : 0)) return;
  __shared__ float hc[2048];
  __shared__ float h2s[512];
  __shared__ float h3s[256];
  int b = blockIdx.x, tid = threadIdx.x;
  for (int k = tid; k < 1024; k += 512){
    hc[k]        = key2f(hmaxk[b*1024 + k]);
    hc[1024 + k] = hsum[b*1024 + k] * (1.0f/2048.0f);
  }
  __syncthreads();
  {
    float acc = 0.f;
    for (int cc = 0; cc < 2048; cc += 8){
      float w[8];
      wload8<BF>(Wl1, (size_t)tid*2048 + cc, w);
      #pragma unroll
      for (int u = 0; u < 8; ++u) acc += w[u]*hc[cc+u];
    }
    float g = wget<BF>(bn6, tid), be = wget<BF>(bn6, 512+tid),
          mu = wget<BF>(bn6, 1024+tid), va = wget<BF>(bn6, 1536+tid);
    float sc = g / sqrtf(va + 1e-5f);
    h2s[tid] = lrelu((acc - mu)*sc + be);
  }
  __syncthreads();
  if (tid < 256){
    float acc = 0.f;
    for (int cc = 0; cc < 512; cc += 8){
      float w[8];
      wload8<BF>(Wl2, (size_t)tid*512 + cc, w);
      #pragma unroll
      for (int u = 0; u < 8; ++u) acc += w[u]*h2s[cc+u];
    }
    acc += wget<BF>(bl2, tid);
    float g = wget<BF>(bn7, tid), be = wget<BF>(bn7, 256+tid),
          mu = wget<BF>(bn7, 512+tid), va = wget<BF>(bn7, 768+tid);
    float sc = g / sqrtf(va + 1e-5f);
    h3s[tid] = lrelu((acc - mu)*sc + be);
  }
  __syncthreads();
  if (tid < 40){
    float acc = 0.f;
    for (int cc = 0; cc < 256; cc += 8){
      float w[8];
      wload8<BF>(Wl3, (size_t)tid*256 + cc, w);
      #pragma unroll
      for (int u = 0; u < 8; ++u) acc += w[u]*h3s[cc+u];
    }
    acc += wget<BF>(bl3, tid);
    if (BF) ((u16*)out)[b*40 + tid] = f2bu(acc);
    else    ((float*)out)[b*40 + tid] = acc;
  }
}

extern "C" void kernel_launch(void* const* d_in, const int* in_sizes, int n_in,
                              void* d_out, int out_size, void* d_ws, size_t ws_size,
                              hipStream_t stream){
  const void* x   = d_in[0];
  const void* W1  = d_in[1];
  const void* bn1 = d_in[2];
  const void* W2  = d_in[3];
  const void* bn2 = d_in[4];
  const void* W3  = d_in[5];
  const void* bn3 = d_in[6];
  const void* W4  = d_in[7];
  const void* bn4 = d_in[8];
  const void* W5  = d_in[9];
  const void* bn5 = d_in[10];
  const void* Wl1 = d_in[11];
  const void* bn6 = d_in[12];
  const void* Wl2 = d_in[13];
  const void* bl2 = d_in[14];
  const void* bn7 = d_in[15];
  const void* Wl3 = d_in[16];
  const void* bl3 = d_in[17];

  // ---- workspace layout (bytes); base total 15,859,968 (proven-safe envelope) ------
  char* base = (char*)d_ws;
  int*   FLAG  = (int*)  (base + 0);
  float* XT    = (float*)(base + 256);
  float* SQ    = (float*)(base + 393472);
  u32*   HMAXK = (u32*)  (base + 524544);
  float* HSUM  = (float*)(base + 590080);
  u16*   IDX1  = (u16*)  (base + 655616);
  u16*   IDX   = (u16*)  (base + 1966336);
  u16*   X2    = (u16*)  (base + 3277056);
  u16*   X3    = (u16*)  (base + 7471360);
  u16*   X1    = X3;                            // aliases X3: x1 dead before EC3 writes x3
  // optional pre-converted bf16 weights (guards on ws_size; rounds 13-15 proved fit)
  u16*   W4B   = (u16*)  (base + 15859968);     //   131,072 B
  u16*   W5B   = (u16*)  (base + 15991040);     // 1,048,576 B -> 17,039,616
  u16*   W2B   = (u16*)  (base + 17039616);     //    16,384 B
  u16*   W3B   = (u16*)  (base + 17056000);     //    32,768 B -> 17,088,768
  const bool pre  = (ws_size >= (size_t)17039616);
  const bool pre2 = (ws_size >= (size_t)17088768);

  dim3 knnG1(NN/64, BB);
  dim3 knnGM(NN/16, BB);      // MFMA KNN: 16 queries/block, 4 segments

  k_detect<<<1, 256, 0, stream>>>((const u16*)x, FLAG);

  if (pre){
    k_wconv<<<(65536 + 255)/256, 256, 0, stream>>>(FLAG, W4, W4B, 65536);
    k_wconv<<<(524288 + 255)/256, 256, 0, stream>>>(FLAG, W5, W5B, 524288);
  }
  if (pre2){
    k_wconv<<<(8192 + 255)/256, 256, 0, stream>>>(FLAG, W2, W2B, 8192);
    k_wconv<<<(16384 + 255)/256, 256, 0, stream>>>(FLAG, W3, W3B, 16384);
  }

  k_prep<true ><<<PP/256, 256, 0, stream>>>(FLAG, x, XT, SQ, HMAXK, HSUM);
  k_prep<false><<<PP/256, 256, 0, stream>>>(FLAG, x, XT, SQ, HMAXK, HSUM);

  // EC1: XT (C=3) -> x1
  k_knn<3,128><<<knnG1, 256, 0, stream>>>(XT, SQ, IDX1);
  k_ec1<true ><<<PP/4, 256, 0, stream>>>(FLAG, XT, IDX1, W1, bn1, X1);
  k_ec1<false><<<PP/4, 256, 0, stream>>>(FLAG, XT, IDX1, W1, bn1, X1);

  // EC2: x1 -> x2 (MFMA edgeconv)
  k_sq<64><<<PP/256, 256, 0, stream>>>(X1, SQ);
  k_knn_mfma<64><<<knnGM, 256, 0, stream>>>(X1, SQ, IDX);
  if (pre2){
    k_ec<64,true ,true ><<<PP/8, 256, 0, stream>>>(FLAG, X1, IDX, W2B, bn2, X2);
    k_ec<64,false,true ><<<PP/8, 256, 0, stream>>>(FLAG, X1, IDX, W2B, bn2, X2);
  } else {
    k_ec<64,true ,false><<<PP/8, 256, 0, stream>>>(FLAG, X1, IDX, W2, bn2, X2);
    k_ec<64,false,false><<<PP/8, 256, 0, stream>>>(FLAG, X1, IDX, W2, bn2, X2);
  }

  // EC3: x2 -> x3 (overwrites x1 region)
  k_sq<64><<<PP/256, 256, 0, stream>>>(X2, SQ);
  k_knn_mfma<64><<<knnGM, 256, 0, stream>>>(X2, SQ, IDX);
  if (pre2){
    k_ec<128,true ,true ><<<PP/8, 256, 0, stream>>>(FLAG, X2, IDX, W3B, bn3, X3);
    k_ec<128,false,true ><<<PP/8, 256, 0, stream>>>(FLAG, X2, IDX, W3B, bn3, X3);
  } else {
    k_ec<128,true ,false><<<PP/8, 256, 0, stream>>>(FLAG, X2, IDX, W3, bn3, X3);
    k_ec<128,false,false><<<PP/8, 256, 0, stream>>>(FLAG, X2, IDX, W3, bn3, X3);
  }

  // EC4 KNN only (x4 recomputed inside k_w5f)
  k_sq<128><<<PP/256, 256, 0, stream>>>(X3, SQ);
  k_knn_mfma<128><<<knnGM, 256, 0, stream>>>(X3, SQ, IDX);

  // fused x1/x4 recompute + W5 + bn5 + act + global max/mean pooling (PTS=16)
  if (pre){
    k_w5f<true ,true ><<<PP/PTS, 512, 0, stream>>>(FLAG, XT, IDX1, X2, X3, IDX,
                                                   W1, bn1, W4B, bn4, W5B, bn5, HMAXK, HSUM);
    k_w5f<false,true ><<<PP/PTS, 512, 0, stream>>>(FLAG, XT, IDX1, X2, X3, IDX,
                                                   W1, bn1, W4B, bn4, W5B, bn5, HMAXK, HSUM);
  } else {
    k_w5f<true ,false><<<PP/PTS, 512, 0, stream>>>(FLAG, XT, IDX1, X2, X3, IDX,
                                                   W1, bn1, W4, bn4, W5, bn5, HMAXK, HSUM);
    k_w5f<false,false><<<PP/PTS, 512, 0, stream>>>(FLAG, XT, IDX1, X2, X3, IDX,
                                                   W1, bn1, W4, bn4, W5, bn5, HMAXK, HSUM);
  }

  // head FCs
  k_head<true ><<<BB, 512, 0, stream>>>(FLAG, HMAXK, HSUM, Wl1, bn6, Wl2, bl2, bn7, Wl3, bl3, d_out);
  k_head<false><<<BB, 512, 0, stream>>>(FLAG, HMAXK, HSUM, Wl1, bn6, Wl2, bl2, bn7, Wl3, bl3, d_out);
}